// Round 3
// baseline (137.088 us; speedup 1.0000x reference)
//
#include <hip/hip_runtime.h>
#include <math.h>

// Problem dims (fixed by setup_inputs): B=2, D=64, H=96, W=96, fp32.
#define BDIM 2
#define DDIM 64
#define HDIM 96
#define WDIM 96
#define HW   (HDIM * WDIM)          // 9216
#define DHW  (DDIM * HDIM * WDIM)   // 589824
#define NVOX (BDIM * DHW)           // 1179648

#define BIGF 1e10f
#define FINF 3.0e38f

#define SIN_STR  100   // padded stride for full-width (96) input rows; 100%32=4 staggers lines
#define SOUT_STR 36    // padded stride for 32-wide W-result rows; 36%32=4 staggers lines

// ---------------------------------------------------------------------------
// Kernel A: mask init + EDT along W + EDT along H, fused per (b,d, w-third).
// grid = B*D*3 = 384 blocks, 256 threads, ~104 KB LDS (1 block/CU).
// Each block holds the FULL 96x96 (h,w) slab of init values (W scan needs the
// whole line) but computes only its 32-wide w-third of outputs, then runs the
// H-pass on that third in LDS and writes the result to global fp/fn once.
// ---------------------------------------------------------------------------
__global__ __launch_bounds__(256, 1) void edt_wh(const float* __restrict__ target,
                                                 float* __restrict__ fp,
                                                 float* __restrict__ fn,
                                                 float* __restrict__ acc) {
    __shared__ float sInP[HDIM * SIN_STR];
    __shared__ float sInN[HDIM * SIN_STR];
    __shared__ float sOutP[HDIM * SOUT_STR];
    __shared__ float sOutN[HDIM * SOUT_STR];
    const int tid   = threadIdx.x;
    const int third = blockIdx.x % 3;
    const int slab  = blockIdx.x / 3;      // b*DDIM + d
    const int w0    = third * 32;
    const int sbase = slab * HW;

    // zero the accumulators + completion counter consumed by kernel B
    if (blockIdx.x == 0) {
        if (tid < 4) acc[tid] = 0.0f;
        if (tid == 4) ((int*)acc)[4] = 0;
    }

    // ---- init: target -> {0, BIG} for both fields, padded rows ----
    for (int t = tid; t < HW / 4; t += 256) {
        float4 tg = ((const float4*)(target + sbase))[t];
        int e = t * 4;
        int h = e / WDIM;                   // 4 elems never cross a row (96%4==0)
        int w = e - h * WDIM;
        float4 ip, in_;
        ip.x = tg.x > 0.5f ? BIGF : 0.0f;  in_.x = tg.x > 0.5f ? 0.0f : BIGF;
        ip.y = tg.y > 0.5f ? BIGF : 0.0f;  in_.y = tg.y > 0.5f ? 0.0f : BIGF;
        ip.z = tg.z > 0.5f ? BIGF : 0.0f;  in_.z = tg.z > 0.5f ? 0.0f : BIGF;
        ip.w = tg.w > 0.5f ? BIGF : 0.0f;  in_.w = tg.w > 0.5f ? 0.0f : BIGF;
        *(float4*)&sInP[h * SIN_STR + w] = ip;
        *(float4*)&sInN[h * SIN_STR + w] = in_;
    }
    __syncthreads();

    // ---- W pass: 8 threads/line x 4 contiguous outputs; 3 chunks of 32 lines ----
    {
        const int c     = tid & 7;
        const int lbase = tid >> 3;        // 0..31
        const float wc0 = (float)(w0 + 4 * c);
        for (int ch = 0; ch < 3; ++ch) {
            const int l = ch * 32 + lbase;
            const float4* rp = (const float4*)&sInP[l * SIN_STR];
            const float4* rn = (const float4*)&sInN[l * SIN_STR];
            float4 mp = {FINF, FINF, FINF, FINF};
            float4 mn = {FINF, FINF, FINF, FINF};
            #pragma unroll 4
            for (int j4 = 0; j4 < WDIM / 4; ++j4) {
                float4 p = rp[j4];
                float4 n = rn[j4];
                #pragma unroll
                for (int jj = 0; jj < 4; ++jj) {
                    float pv = jj == 0 ? p.x : jj == 1 ? p.y : jj == 2 ? p.z : p.w;
                    float nv = jj == 0 ? n.x : jj == 1 ? n.y : jj == 2 ? n.z : n.w;
                    float d0 = wc0 - (float)(4 * j4 + jj);
                    float d1 = d0 + 1.f, d2 = d0 + 2.f, d3 = d0 + 3.f;
                    mp.x = fminf(mp.x, fmaf(d0, d0, pv));
                    mp.y = fminf(mp.y, fmaf(d1, d1, pv));
                    mp.z = fminf(mp.z, fmaf(d2, d2, pv));
                    mp.w = fminf(mp.w, fmaf(d3, d3, pv));
                    mn.x = fminf(mn.x, fmaf(d0, d0, nv));
                    mn.y = fminf(mn.y, fmaf(d1, d1, nv));
                    mn.z = fminf(mn.z, fmaf(d2, d2, nv));
                    mn.w = fminf(mn.w, fmaf(d3, d3, nv));
                }
            }
            *(float4*)&sOutP[l * SOUT_STR + 4 * c] = mp;
            *(float4*)&sOutN[l * SOUT_STR + 4 * c] = mn;
        }
    }
    __syncthreads();

    // ---- H pass on the 32-wide third: thread owns float4-col q, rows r0,+32,+64 ----
    {
        const int q  = tid & 7;
        const int r0 = tid >> 3;           // 0..31
        float4 hp[3], hn[3];
        #pragma unroll
        for (int k = 0; k < 3; ++k) {
            hp[k] = make_float4(FINF, FINF, FINF, FINF);
            hn[k] = make_float4(FINF, FINF, FINF, FINF);
        }
        const float4* rp = (const float4*)sOutP;   // row j -> index j*(SOUT_STR/4)
        const float4* rn = (const float4*)sOutN;
        float dd = (float)r0;
        #pragma unroll 2
        for (int j = 0; j < HDIM; ++j) {
            float4 p = rp[j * (SOUT_STR / 4) + q];
            float4 n = rn[j * (SOUT_STR / 4) + q];
            #pragma unroll
            for (int k = 0; k < 3; ++k) {
                float d  = dd + (float)(32 * k);
                float d2 = d * d;          // exact integer in f32
                hp[k].x = fminf(hp[k].x, d2 + p.x);
                hp[k].y = fminf(hp[k].y, d2 + p.y);
                hp[k].z = fminf(hp[k].z, d2 + p.z);
                hp[k].w = fminf(hp[k].w, d2 + p.w);
                hn[k].x = fminf(hn[k].x, d2 + n.x);
                hn[k].y = fminf(hn[k].y, d2 + n.y);
                hn[k].z = fminf(hn[k].z, d2 + n.z);
                hn[k].w = fminf(hn[k].w, d2 + n.w);
            }
            dd -= 1.f;
        }
        #pragma unroll
        for (int k = 0; k < 3; ++k) {
            int g = sbase + (r0 + 32 * k) * WDIM + w0 + 4 * q;
            *(float4*)&fp[g] = hp[k];
            *(float4*)&fn[g] = hn[k];
        }
    }
}

// ---------------------------------------------------------------------------
// Kernel B: EDT along D + fused loss epilogue + per-batch reduction + finalize
// via last-block-done counter. Tile = one (b,h) x 64 d x 32 w. grid = B*H*3.
// ---------------------------------------------------------------------------
__device__ __forceinline__ void accum_loss(float mpv, float mnv, float p, float t,
                                           float& num, float& den) {
    float dp = sqrtf(mpv);
    float dn = sqrtf(mnv);
    float a  = fabsf(dn - dp);
    float w;
    if (a <= 3.0f)      w = 1.0f;
    else if (a >= 5.0f) w = 0.0f;
    else                w = 1.0f - (a - 3.0f) * 0.5f;
    float lp = fmaxf(logf(p), -100.0f);
    float l1 = fmaxf(logf(1.0f - p), -100.0f);
    float bce = -(t * lp + (1.0f - t) * l1);
    num += bce * w;
    den += w;
}

__global__ __launch_bounds__(256) void edt_d_loss(const float* __restrict__ fp,
                                                  const float* __restrict__ fn,
                                                  const float* __restrict__ pred,
                                                  const float* __restrict__ target,
                                                  float* __restrict__ acc,
                                                  float* __restrict__ out) {
    __shared__ float sfp[DDIM * 32];
    __shared__ float sfn[DDIM * 32];
    __shared__ float rsum[8];
    const int tid = threadIdx.x;
    const int w0  = (blockIdx.x % 3) * 32;
    const int bh  = blockIdx.x / 3;
    const int b   = bh / HDIM;
    const int h   = bh - b * HDIM;
    const int base = b * DHW + h * WDIM + w0;   // element (d, wi) -> base + d*HW + wi

    for (int t = tid; t < DDIM * 32; t += 256) {
        int d = t >> 5, wi = t & 31;
        int g = base + d * HW + wi;
        sfp[t] = fp[g];
        sfn[t] = fn[g];
    }
    __syncthreads();

    const int q  = tid & 7;
    const int r0 = tid >> 3;                    // 0..31; rows r0, r0+32
    float4 mp[2], mn[2];
    #pragma unroll
    for (int k = 0; k < 2; ++k) {
        mp[k] = make_float4(FINF, FINF, FINF, FINF);
        mn[k] = make_float4(FINF, FINF, FINF, FINF);
    }
    const float4* rp = ((const float4*)sfp) + q;
    const float4* rn = ((const float4*)sfn) + q;

    float dd = (float)r0;
    #pragma unroll 2
    for (int j = 0; j < DDIM; ++j) {
        float4 p = rp[j * 8];
        float4 n = rn[j * 8];
        #pragma unroll
        for (int k = 0; k < 2; ++k) {
            float d  = dd + (float)(32 * k);
            float d2 = d * d;
            mp[k].x = fminf(mp[k].x, d2 + p.x);
            mp[k].y = fminf(mp[k].y, d2 + p.y);
            mp[k].z = fminf(mp[k].z, d2 + p.z);
            mp[k].w = fminf(mp[k].w, d2 + p.w);
            mn[k].x = fminf(mn[k].x, d2 + n.x);
            mn[k].y = fminf(mn[k].y, d2 + n.y);
            mn[k].z = fminf(mn[k].z, d2 + n.z);
            mn[k].w = fminf(mn[k].w, d2 + n.w);
        }
        dd -= 1.f;
    }

    float num = 0.f, den = 0.f;
    #pragma unroll
    for (int k = 0; k < 2; ++k) {
        int g = base + (r0 + 32 * k) * HW + q * 4;
        float4 pr = *(const float4*)&pred[g];
        float4 tg = *(const float4*)&target[g];
        accum_loss(mp[k].x, mn[k].x, pr.x, tg.x, num, den);
        accum_loss(mp[k].y, mn[k].y, pr.y, tg.y, num, den);
        accum_loss(mp[k].z, mn[k].z, pr.z, tg.z, num, den);
        accum_loss(mp[k].w, mn[k].w, pr.w, tg.w, num, den);
    }

    // wave (64) reduce, then cross-wave via LDS, then one atomic pair per block
    for (int off = 32; off > 0; off >>= 1) {
        num += __shfl_down(num, off);
        den += __shfl_down(den, off);
    }
    if ((tid & 63) == 0) {
        rsum[tid >> 6]       = num;
        rsum[4 + (tid >> 6)] = den;
    }
    __syncthreads();
    if (tid == 0) {
        float ns = rsum[0] + rsum[1] + rsum[2] + rsum[3];
        float ds = rsum[4] + rsum[5] + rsum[6] + rsum[7];
        atomicAdd(&acc[b], ns);
        atomicAdd(&acc[2 + b], ds);
        __threadfence();
        int done = atomicAdd((int*)acc + 4, 1);
        if (done == BDIM * HDIM * 3 - 1) {      // last block: finalize
            __threadfence();
            float n0 = atomicAdd(&acc[0], 0.0f);
            float n1 = atomicAdd(&acc[1], 0.0f);
            float d0 = atomicAdd(&acc[2], 0.0f);
            float d1 = atomicAdd(&acc[3], 0.0f);
            out[0] = 0.5f * (n0 / (d0 + 1e-5f) + n1 / (d1 + 1e-5f));
        }
    }
}

extern "C" void kernel_launch(void* const* d_in, const int* in_sizes, int n_in,
                              void* d_out, int out_size, void* d_ws, size_t ws_size,
                              hipStream_t stream) {
    const float* pred   = (const float*)d_in[0];
    const float* target = (const float*)d_in[1];
    float* fp  = (float*)d_ws;          // NVOX floats
    float* fn  = fp + NVOX;             // NVOX floats
    float* acc = fn + NVOX;             // 4 floats num/den + 1 int counter
    float* out = (float*)d_out;

    edt_wh<<<BDIM * DDIM * 3, 256, 0, stream>>>(target, fp, fn, acc);
    edt_d_loss<<<BDIM * HDIM * 3, 256, 0, stream>>>(fp, fn, pred, target, acc, out);
}

// Round 4
// 127.580 us; speedup vs baseline: 1.0745x; 1.0745x over previous
//
#include <hip/hip_runtime.h>
#include <math.h>

// Problem dims (fixed by setup_inputs): B=2, D=64, H=96, W=96, fp32.
#define BDIM 2
#define DDIM 64
#define HDIM 96
#define WDIM 96
#define HW   (HDIM * WDIM)          // 9216
#define DHW  (DDIM * HDIM * WDIM)   // 589824
#define NVOX (BDIM * DHW)           // 1179648

#define BIGF 1e10f
#define FINF 3.0e38f

// ---------------------------------------------------------------------------
// Kernel 1: init f_pos/f_neg from target and EDT pass along W (contiguous).
// 16 lines of 96 per block, 256 threads = 16 threads/line, 6 outputs/thread
// (strided by 16) so each LDS float4 read feeds 6 outputs. Line stride padded
// to 100 floats (100%32=4) so the 4 lines per wave hit disjoint banks.
// LDS 12.8 KB -> many blocks/CU. Also zeroes acc + completion counter.
// ---------------------------------------------------------------------------
#define LSTR 100
__global__ __launch_bounds__(256) void edt_pass_w(const float* __restrict__ target,
                                                  float* __restrict__ fp,
                                                  float* __restrict__ fn,
                                                  float* __restrict__ acc) {
    __shared__ float sfp[16 * LSTR];
    __shared__ float sfn[16 * LSTR];
    const int tid  = threadIdx.x;
    const int base = blockIdx.x * (16 * WDIM);

    if (blockIdx.x == 0) {
        if (tid < 4) acc[tid] = 0.0f;           // num[2], den[2]
        if (tid == 4) ((int*)acc)[4] = 0;       // completion counter for pass D
    }

    for (int t = tid; t < 16 * WDIM; t += 256) {
        int l = t / WDIM;
        int i = t - l * WDIM;
        float tg = target[base + t];
        bool  m  = tg > 0.5f;
        sfp[l * LSTR + i] = m ? BIGF : 0.0f;
        sfn[l * LSTR + i] = m ? 0.0f : BIGF;
    }
    __syncthreads();

    const int c = tid & 15;          // lane within line
    const int l = tid >> 4;          // line 0..15
    const float4* rp = (const float4*)&sfp[l * LSTR];
    const float4* rn = (const float4*)&sfn[l * LSTR];

    float mp[6], mn[6];
    #pragma unroll
    for (int r = 0; r < 6; ++r) { mp[r] = FINF; mn[r] = FINF; }

    const float fc = (float)c;
    #pragma unroll 2
    for (int j4 = 0; j4 < WDIM / 4; ++j4) {
        float4 p = rp[j4];
        float4 n = rn[j4];
        float db = fc - (float)(4 * j4);   // d for r=0 at lane .x
        #pragma unroll
        for (int jj = 0; jj < 4; ++jj) {
            float pv = jj == 0 ? p.x : jj == 1 ? p.y : jj == 2 ? p.z : p.w;
            float nv = jj == 0 ? n.x : jj == 1 ? n.y : jj == 2 ? n.z : n.w;
            float d0 = db - (float)jj;
            #pragma unroll
            for (int r = 0; r < 6; ++r) {
                float d = d0 + (float)(16 * r);
                mp[r] = fminf(mp[r], fmaf(d, d, pv));
                mn[r] = fminf(mn[r], fmaf(d, d, nv));
            }
        }
    }
    #pragma unroll
    for (int r = 0; r < 6; ++r) {
        int g = base + l * WDIM + c + 16 * r;
        fp[g] = mp[r];
        fn[g] = mn[r];
    }
}

// ---------------------------------------------------------------------------
// Kernel 2: EDT pass along H. Tile = one (b,d) slab x 96 h x 32 w.
// grid = B*D*3 = 384, LDS 24 KB (-> ~5 blocks/CU). Thread owns float4-col q
// (0..7) and 3 rows {r0, r0+32, r0+64}: each LDS float4 read feeds 3 rows.
// In-place (tiles partition the array).
// ---------------------------------------------------------------------------
__global__ __launch_bounds__(256) void edt_pass_h(float* __restrict__ fp,
                                                  float* __restrict__ fn) {
    __shared__ float sfp[HDIM * 32];
    __shared__ float sfn[HDIM * 32];
    const int tid  = threadIdx.x;
    const int slab = blockIdx.x / 3;            // b*D + d
    const int w0   = (blockIdx.x % 3) * 32;
    const int base = slab * HW + w0;            // element (h, wi) -> base + h*W + wi

    for (int t = tid; t < HDIM * 32; t += 256) {
        int h = t >> 5, wi = t & 31;
        int g = base + h * WDIM + wi;
        sfp[t] = fp[g];
        sfn[t] = fn[g];
    }
    __syncthreads();

    const int q  = tid & 7;
    const int r0 = tid >> 3;                    // 0..31
    float4 mp[3], mn[3];
    #pragma unroll
    for (int k = 0; k < 3; ++k) {
        mp[k] = make_float4(FINF, FINF, FINF, FINF);
        mn[k] = make_float4(FINF, FINF, FINF, FINF);
    }
    const float4* rp = ((const float4*)sfp) + q;
    const float4* rn = ((const float4*)sfn) + q;

    float dd = (float)r0;
    #pragma unroll 2
    for (int j = 0; j < HDIM; ++j) {
        float4 p = rp[j * 8];
        float4 n = rn[j * 8];
        #pragma unroll
        for (int k = 0; k < 3; ++k) {
            float d  = dd + (float)(32 * k);
            float d2 = d * d;                   // exact integer in f32
            mp[k].x = fminf(mp[k].x, d2 + p.x);
            mp[k].y = fminf(mp[k].y, d2 + p.y);
            mp[k].z = fminf(mp[k].z, d2 + p.z);
            mp[k].w = fminf(mp[k].w, d2 + p.w);
            mn[k].x = fminf(mn[k].x, d2 + n.x);
            mn[k].y = fminf(mn[k].y, d2 + n.y);
            mn[k].z = fminf(mn[k].z, d2 + n.z);
            mn[k].w = fminf(mn[k].w, d2 + n.w);
        }
        dd -= 1.f;
    }
    #pragma unroll
    for (int k = 0; k < 3; ++k) {
        int g = base + (r0 + 32 * k) * WDIM + q * 4;
        *(float4*)&fp[g] = mp[k];
        *(float4*)&fn[g] = mn[k];
    }
}

// ---------------------------------------------------------------------------
// Kernel 3: EDT pass along D + fused loss epilogue + per-batch reduction +
// finalize via last-block-done counter. Tile = one (b,h) x 64 d x 32 w.
// grid = B*H*3 = 576, LDS 16 KB.
// ---------------------------------------------------------------------------
__device__ __forceinline__ void accum_loss(float mpv, float mnv, float p, float t,
                                           float& num, float& den) {
    float dp = sqrtf(mpv);
    float dn = sqrtf(mnv);
    float a  = fabsf(dn - dp);
    float w;
    if (a <= 3.0f)      w = 1.0f;
    else if (a >= 5.0f) w = 0.0f;
    else                w = 1.0f - (a - 3.0f) * 0.5f;
    float lp = fmaxf(logf(p), -100.0f);
    float l1 = fmaxf(logf(1.0f - p), -100.0f);
    float bce = -(t * lp + (1.0f - t) * l1);
    num += bce * w;
    den += w;
}

__global__ __launch_bounds__(256) void edt_pass_d_loss(const float* __restrict__ fp,
                                                       const float* __restrict__ fn,
                                                       const float* __restrict__ pred,
                                                       const float* __restrict__ target,
                                                       float* __restrict__ acc,
                                                       float* __restrict__ out) {
    __shared__ float sfp[DDIM * 32];
    __shared__ float sfn[DDIM * 32];
    __shared__ float rsum[8];
    const int tid = threadIdx.x;
    const int w0  = (blockIdx.x % 3) * 32;
    const int bh  = blockIdx.x / 3;
    const int b   = bh / HDIM;
    const int h   = bh - b * HDIM;
    const int base = b * DHW + h * WDIM + w0;   // element (d, wi) -> base + d*HW + wi

    for (int t = tid; t < DDIM * 32; t += 256) {
        int d = t >> 5, wi = t & 31;
        int g = base + d * HW + wi;
        sfp[t] = fp[g];
        sfn[t] = fn[g];
    }
    __syncthreads();

    const int q  = tid & 7;
    const int r0 = tid >> 3;                    // 0..31; rows r0, r0+32
    float4 mp[2], mn[2];
    #pragma unroll
    for (int k = 0; k < 2; ++k) {
        mp[k] = make_float4(FINF, FINF, FINF, FINF);
        mn[k] = make_float4(FINF, FINF, FINF, FINF);
    }
    const float4* rp = ((const float4*)sfp) + q;
    const float4* rn = ((const float4*)sfn) + q;

    float dd = (float)r0;
    #pragma unroll 2
    for (int j = 0; j < DDIM; ++j) {
        float4 p = rp[j * 8];
        float4 n = rn[j * 8];
        #pragma unroll
        for (int k = 0; k < 2; ++k) {
            float d  = dd + (float)(32 * k);
            float d2 = d * d;
            mp[k].x = fminf(mp[k].x, d2 + p.x);
            mp[k].y = fminf(mp[k].y, d2 + p.y);
            mp[k].z = fminf(mp[k].z, d2 + p.z);
            mp[k].w = fminf(mp[k].w, d2 + p.w);
            mn[k].x = fminf(mn[k].x, d2 + n.x);
            mn[k].y = fminf(mn[k].y, d2 + n.y);
            mn[k].z = fminf(mn[k].z, d2 + n.z);
            mn[k].w = fminf(mn[k].w, d2 + n.w);
        }
        dd -= 1.f;
    }

    float num = 0.f, den = 0.f;
    #pragma unroll
    for (int k = 0; k < 2; ++k) {
        int g = base + (r0 + 32 * k) * HW + q * 4;
        float4 pr = *(const float4*)&pred[g];
        float4 tg = *(const float4*)&target[g];
        accum_loss(mp[k].x, mn[k].x, pr.x, tg.x, num, den);
        accum_loss(mp[k].y, mn[k].y, pr.y, tg.y, num, den);
        accum_loss(mp[k].z, mn[k].z, pr.z, tg.z, num, den);
        accum_loss(mp[k].w, mn[k].w, pr.w, tg.w, num, den);
    }

    // wave (64) reduce, then cross-wave via LDS, then one atomic pair per block
    for (int off = 32; off > 0; off >>= 1) {
        num += __shfl_down(num, off);
        den += __shfl_down(den, off);
    }
    if ((tid & 63) == 0) {
        rsum[tid >> 6]       = num;
        rsum[4 + (tid >> 6)] = den;
    }
    __syncthreads();
    if (tid == 0) {
        float ns = rsum[0] + rsum[1] + rsum[2] + rsum[3];
        float ds = rsum[4] + rsum[5] + rsum[6] + rsum[7];
        atomicAdd(&acc[b], ns);
        atomicAdd(&acc[2 + b], ds);
        __threadfence();
        int done = atomicAdd((int*)acc + 4, 1);
        if (done == BDIM * HDIM * 3 - 1) {      // last block: finalize
            __threadfence();
            float n0 = atomicAdd(&acc[0], 0.0f);
            float n1 = atomicAdd(&acc[1], 0.0f);
            float d0 = atomicAdd(&acc[2], 0.0f);
            float d1 = atomicAdd(&acc[3], 0.0f);
            out[0] = 0.5f * (n0 / (d0 + 1e-5f) + n1 / (d1 + 1e-5f));
        }
    }
}

extern "C" void kernel_launch(void* const* d_in, const int* in_sizes, int n_in,
                              void* d_out, int out_size, void* d_ws, size_t ws_size,
                              hipStream_t stream) {
    const float* pred   = (const float*)d_in[0];
    const float* target = (const float*)d_in[1];
    float* fp  = (float*)d_ws;          // NVOX floats
    float* fn  = fp + NVOX;             // NVOX floats
    float* acc = fn + NVOX;             // 4 floats num/den + 1 int counter
    float* out = (float*)d_out;

    edt_pass_w<<<BDIM * DDIM * HDIM / 16, 256, 0, stream>>>(target, fp, fn, acc);
    edt_pass_h<<<BDIM * DDIM * 3, 256, 0, stream>>>(fp, fn);
    edt_pass_d_loss<<<BDIM * HDIM * 3, 256, 0, stream>>>(fp, fn, pred, target, acc, out);
}

// Round 5
// 95.523 us; speedup vs baseline: 1.4351x; 1.3356x over previous
//
#include <hip/hip_runtime.h>
#include <math.h>

// Problem dims (fixed by setup_inputs): B=2, D=64, H=96, W=96, fp32.
#define BDIM 2
#define DDIM 64
#define HDIM 96
#define WDIM 96
#define HW   (HDIM * WDIM)          // 9216
#define DHW  (DDIM * HDIM * WDIM)   // 589824
#define NVOX (BDIM * DHW)           // 1179648

#define BIGF 1e10f

// Window optimization: loss weight w = 0 whenever a >= 5 (and per voxel one of
// dp,dn is exactly 0, so a = the nonzero one). Capping every squared distance
// at 25 preserves w BIT-EXACTLY: values < 25 propagate exactly (their argmin
// lies within +-4 in each axis), values >= 25 clamp to exactly 25 -> a=5 -> w=0.
// So each 1D pass scans only j in [i-4, i+4] and caps at 25.

// ---------------------------------------------------------------------------
// Kernel 1: EDT along W directly from the mask (no {0,BIG} init field).
// 16 lines of 96 per block, 256 threads, LDS line stride 104 (4-halo each
// side, sentinel 0.5 = "neither class"). Thread c owns outputs c+16r.
// Also zeroes the 4 accumulators.
// ---------------------------------------------------------------------------
#define K1_LSTR 104
__global__ __launch_bounds__(256) void edt_pass_w(const float* __restrict__ target,
                                                  float* __restrict__ fp,
                                                  float* __restrict__ fn,
                                                  float* __restrict__ acc) {
    __shared__ float sm[16 * K1_LSTR];
    const int tid  = threadIdx.x;
    const int base = blockIdx.x * (16 * WDIM);

    if (blockIdx.x == 0 && tid < 4) acc[tid] = 0.0f;

    if (tid < 128) {                       // halo: 16 lines x 8 slots
        int l = tid >> 3, s = tid & 7;
        sm[l * K1_LSTR + (s < 4 ? s : 96 + s)] = 0.5f;  // 0..3, 100..103
    }
    for (int t = tid; t < 16 * WDIM; t += 256) {
        int l = t / WDIM;
        int i = t - l * WDIM;
        sm[l * K1_LSTR + 4 + i] = target[base + t];
    }
    __syncthreads();

    const int c = tid & 15;                // output column group
    const int l = tid >> 4;                // line 0..15
    const float* line = &sm[l * K1_LSTR];

    float sp[6], sn[6];
    #pragma unroll
    for (int r = 0; r < 6; ++r) { sp[r] = 25.0f; sn[r] = 25.0f; }

    #pragma unroll
    for (int d = -4; d <= 4; ++d) {
        const float d2 = (float)(d * d);
        #pragma unroll
        for (int r = 0; r < 6; ++r) {
            float m  = line[4 + c + 16 * r + d];
            bool  fg = m > 0.5f;           // sentinel 0.5 -> neither class
            sp[r] = fminf(sp[r], fg ? BIGF : d2);   // dist to nearest bg
            sn[r] = fminf(sn[r], fg ? d2 : BIGF);   // dist to nearest fg
        }
    }
    #pragma unroll
    for (int r = 0; r < 6; ++r) {
        int g = base + l * WDIM + c + 16 * r;
        fp[g] = sp[r];
        fn[g] = sn[r];
    }
}

// ---------------------------------------------------------------------------
// Kernel 2: EDT along H, window +-4. Tile = (b,d) slab x 96h x 32w, rows
// padded +4 halo each side (BIGF), row stride 36 (36%32=4 staggers banks).
// Thread owns float4-col q and rows {r0, r0+32, r0+64}. In-place.
// ---------------------------------------------------------------------------
#define K2_STR 36
__global__ __launch_bounds__(256) void edt_pass_h(float* __restrict__ fp,
                                                  float* __restrict__ fn) {
    __shared__ float sfp[104 * K2_STR];
    __shared__ float sfn[104 * K2_STR];
    const int tid  = threadIdx.x;
    const int slab = blockIdx.x / 3;
    const int w0   = (blockIdx.x % 3) * 32;
    const int base = slab * HW + w0;

    {   // halo rows 0..3 and 100..103
        int s = tid >> 5, wi = tid & 31;
        int r = (s < 4) ? s : 96 + s;
        sfp[r * K2_STR + wi] = BIGF;
        sfn[r * K2_STR + wi] = BIGF;
    }
    for (int t = tid; t < HDIM * 32; t += 256) {
        int h = t >> 5, wi = t & 31;
        int g = base + h * WDIM + wi;
        sfp[(h + 4) * K2_STR + wi] = fp[g];
        sfn[(h + 4) * K2_STR + wi] = fn[g];
    }
    __syncthreads();

    const int q  = tid & 7;
    const int r0 = tid >> 3;               // 0..31
    #pragma unroll
    for (int k = 0; k < 3; ++k) {
        const int row = r0 + 32 * k;
        float4 mp = {25.f, 25.f, 25.f, 25.f};   // init 25 == cap
        float4 mn = {25.f, 25.f, 25.f, 25.f};
        #pragma unroll
        for (int t9 = 0; t9 < 9; ++t9) {
            const int pr = row + t9;       // padded row index (row-4+t9)+4
            const float d  = (float)(t9 - 4);
            const float d2 = d * d;
            float4 p = *(const float4*)&sfp[pr * K2_STR + q * 4];
            float4 n = *(const float4*)&sfn[pr * K2_STR + q * 4];
            mp.x = fminf(mp.x, d2 + p.x);
            mp.y = fminf(mp.y, d2 + p.y);
            mp.z = fminf(mp.z, d2 + p.z);
            mp.w = fminf(mp.w, d2 + p.w);
            mn.x = fminf(mn.x, d2 + n.x);
            mn.y = fminf(mn.y, d2 + n.y);
            mn.z = fminf(mn.z, d2 + n.z);
            mn.w = fminf(mn.w, d2 + n.w);
        }
        int g = base + row * WDIM + q * 4;
        *(float4*)&fp[g] = mp;
        *(float4*)&fn[g] = mn;
    }
}

// ---------------------------------------------------------------------------
// Kernel 3: EDT along D (window +-4) + fused loss + per-batch reduction.
// Tile = (b,h) x 64d x 32w, rows padded +4 halo, stride 36.
// ---------------------------------------------------------------------------
__device__ __forceinline__ void accum_loss(float mpv, float mnv, float p, float t,
                                           float& num, float& den) {
    float dp = sqrtf(mpv);
    float dn = sqrtf(mnv);
    float a  = fabsf(dn - dp);
    float w;
    if (a <= 3.0f)      w = 1.0f;
    else if (a >= 5.0f) w = 0.0f;
    else                w = 1.0f - (a - 3.0f) * 0.5f;
    float lp = fmaxf(logf(p), -100.0f);
    float l1 = fmaxf(logf(1.0f - p), -100.0f);
    float bce = -(t * lp + (1.0f - t) * l1);
    num += bce * w;
    den += w;
}

__global__ __launch_bounds__(256) void edt_pass_d_loss(const float* __restrict__ fp,
                                                       const float* __restrict__ fn,
                                                       const float* __restrict__ pred,
                                                       const float* __restrict__ target,
                                                       float* __restrict__ acc) {
    __shared__ float sfp[72 * K2_STR];
    __shared__ float sfn[72 * K2_STR];
    __shared__ float rsum[8];
    const int tid = threadIdx.x;
    const int w0  = (blockIdx.x % 3) * 32;
    const int bh  = blockIdx.x / 3;
    const int b   = bh / HDIM;
    const int h   = bh - b * HDIM;
    const int base = b * DHW + h * WDIM + w0;   // element (d, wi) -> base + d*HW + wi

    {   // halo rows 0..3 and 68..71
        int s = tid >> 5, wi = tid & 31;
        int r = (s < 4) ? s : 64 + s;
        sfp[r * K2_STR + wi] = BIGF;
        sfn[r * K2_STR + wi] = BIGF;
    }
    for (int t = tid; t < DDIM * 32; t += 256) {
        int d = t >> 5, wi = t & 31;
        int g = base + d * HW + wi;
        sfp[(d + 4) * K2_STR + wi] = fp[g];
        sfn[(d + 4) * K2_STR + wi] = fn[g];
    }
    __syncthreads();

    const int q  = tid & 7;
    const int r0 = tid >> 3;               // 0..31; rows r0, r0+32
    float num = 0.f, den = 0.f;
    #pragma unroll
    for (int k = 0; k < 2; ++k) {
        const int row = r0 + 32 * k;
        float4 mp = {25.f, 25.f, 25.f, 25.f};
        float4 mn = {25.f, 25.f, 25.f, 25.f};
        #pragma unroll
        for (int t9 = 0; t9 < 9; ++t9) {
            const int pr = row + t9;
            const float d  = (float)(t9 - 4);
            const float d2 = d * d;
            float4 p = *(const float4*)&sfp[pr * K2_STR + q * 4];
            float4 n = *(const float4*)&sfn[pr * K2_STR + q * 4];
            mp.x = fminf(mp.x, d2 + p.x);
            mp.y = fminf(mp.y, d2 + p.y);
            mp.z = fminf(mp.z, d2 + p.z);
            mp.w = fminf(mp.w, d2 + p.w);
            mn.x = fminf(mn.x, d2 + n.x);
            mn.y = fminf(mn.y, d2 + n.y);
            mn.z = fminf(mn.z, d2 + n.z);
            mn.w = fminf(mn.w, d2 + n.w);
        }
        int g = base + row * HW + q * 4;
        float4 pr4 = *(const float4*)&pred[g];
        float4 tg4 = *(const float4*)&target[g];
        accum_loss(mp.x, mn.x, pr4.x, tg4.x, num, den);
        accum_loss(mp.y, mn.y, pr4.y, tg4.y, num, den);
        accum_loss(mp.z, mn.z, pr4.z, tg4.z, num, den);
        accum_loss(mp.w, mn.w, pr4.w, tg4.w, num, den);
    }

    // wave (64) reduce, then cross-wave via LDS, then one atomic pair per block
    for (int off = 32; off > 0; off >>= 1) {
        num += __shfl_down(num, off);
        den += __shfl_down(den, off);
    }
    if ((tid & 63) == 0) {
        rsum[tid >> 6]       = num;
        rsum[4 + (tid >> 6)] = den;
    }
    __syncthreads();
    if (tid == 0) {
        float ns = rsum[0] + rsum[1] + rsum[2] + rsum[3];
        float ds = rsum[4] + rsum[5] + rsum[6] + rsum[7];
        atomicAdd(&acc[b], ns);
        atomicAdd(&acc[2 + b], ds);
    }
}

// ---------------------------------------------------------------------------
// Kernel 4: finalize scalar
// ---------------------------------------------------------------------------
__global__ void finalize(const float* __restrict__ acc, float* __restrict__ out) {
    if (threadIdx.x == 0) {
        float r0 = acc[0] / (acc[2] + 1e-5f);
        float r1 = acc[1] / (acc[3] + 1e-5f);
        out[0] = 0.5f * (r0 + r1);
    }
}

extern "C" void kernel_launch(void* const* d_in, const int* in_sizes, int n_in,
                              void* d_out, int out_size, void* d_ws, size_t ws_size,
                              hipStream_t stream) {
    const float* pred   = (const float*)d_in[0];
    const float* target = (const float*)d_in[1];
    float* fp  = (float*)d_ws;          // NVOX floats
    float* fn  = fp + NVOX;             // NVOX floats
    float* acc = fn + NVOX;             // 4 floats: num[2], den[2]
    float* out = (float*)d_out;

    edt_pass_w<<<NVOX / (16 * WDIM), 256, 0, stream>>>(target, fp, fn, acc);
    edt_pass_h<<<BDIM * DDIM * 3, 256, 0, stream>>>(fp, fn);
    edt_pass_d_loss<<<BDIM * HDIM * 3, 256, 0, stream>>>(fp, fn, pred, target, acc);
    finalize<<<1, 64, 0, stream>>>(acc, out);
}

// Round 6
// 95.132 us; speedup vs baseline: 1.4410x; 1.0041x over previous
//
#include <hip/hip_runtime.h>
#include <math.h>

// Problem dims (fixed by setup_inputs): B=2, D=64, H=96, W=96, fp32.
#define BDIM 2
#define DDIM 64
#define HDIM 96
#define WDIM 96
#define HW   (HDIM * WDIM)
#define DHW  (DDIM * HW)

// Window optimization (validated R5, absmax 0.0): capping every squared
// distance at 25 preserves the loss weight BIT-EXACTLY (w=0 for a>=5; exactly
// one of dp,dn is 0 per voxel). So the capped 3D EDT is LOCAL: each output
// needs the mask only within a +-4 halo per axis -> full fusion in one kernel.
//
// Tile per block: (b, 16 d, 8 h, 32 w) interior; halo 4 each side on d,h,w.
// Mask kept as 40-bit rows (fg bits + valid bits) -> W-pass is a 5-step
// nearest-set-bit cndmask chain; W and WH intermediates are uint8 in LDS.
#define DT 16
#define DH 24            // DT + 8
#define HT 8
#define HH 16            // HT + 8
#define WT 32
#define NROWS (DH * HH)  // 384 (d,h) rows of 40 mask bits
#define NBLK  (BDIM * (DDIM / DT) * (HDIM / HT) * (WDIM / WT))  // 288

// ---------------------------------------------------------------------------
// Kernel 1: zero the accumulators + completion counter (ws is poisoned 0xAA).
// ---------------------------------------------------------------------------
__global__ void init_acc(float* __restrict__ acc) {
    if (threadIdx.x < 4) acc[threadIdx.x] = 0.0f;
    if (threadIdx.x == 4) ((int*)acc)[4] = 0;
}

// nearest set bit in a 9-bit window (center = bit 4) -> squared distance,
// 25 if none. Masks: d=0:0x010 d=1:0x028 d=2:0x044 d=3:0x082 d=4:0x101.
__device__ __forceinline__ unsigned nearest2i(unsigned occ) {
    unsigned r = 25u;
    if (occ & 0x101u) r = 16u;
    if (occ & 0x082u) r = 9u;
    if (occ & 0x044u) r = 4u;
    if (occ & 0x028u) r = 1u;
    if (occ & 0x010u) r = 0u;
    return r;
}

// ---------------------------------------------------------------------------
// Kernel 2: fully fused boundary loss. grid = 288 blocks x 256 threads.
// Stages (LDS, 43 KB -> 3 blocks/CU): bitpack mask -> W pass (bits->uint8)
// -> H pass (uint8 9-tap int min-plus) -> D pass + loss + reduction ->
// per-batch atomics -> last-block finalize.
// ---------------------------------------------------------------------------
__global__ __launch_bounds__(256) void boundary_fused(const float* __restrict__ pred,
                                                      const float* __restrict__ target,
                                                      float* __restrict__ acc,
                                                      float* __restrict__ out) {
    __shared__ unsigned fgb[NROWS * 2];      // fg mask bits, 2x u32 per row
    __shared__ unsigned vbb[NROWS * 2];      // valid (in-volume) bits
    __shared__ unsigned char swp[DH * HH * WT];  // W-pass dist2 to bg
    __shared__ unsigned char swn[DH * HH * WT];  // W-pass dist2 to fg
    __shared__ unsigned char whp[DH * HT * WT];  // W+H dist2 to bg
    __shared__ unsigned char whn[DH * HT * WT];  // W+H dist2 to fg
    __shared__ float rsum[8];

    const int tid = threadIdx.x;
    int x = blockIdx.x;
    const int wt = x % 3;  x /= 3;
    const int ht = x % 12; x /= 12;
    const int dt = x % 4;
    const int b  = x / 4;
    const int d0 = dt * DT, h0 = ht * HT, w0 = wt * WT;

    // ---- zero bit arrays ----
    for (int i = tid; i < NROWS * 2; i += 256) { fgb[i] = 0u; vbb[i] = 0u; }
    __syncthreads();

    // ---- load mask region (24d x 16h x 40w) and bitpack along w ----
    for (int idx = tid; idx < NROWS * 10; idx += 256) {
        const int row = idx / 10, q = idx - row * 10;
        const int dr = row >> 4, hr = row & 15;
        const int d = d0 - 4 + dr, h = h0 - 4 + hr;
        if (d < 0 || d >= DDIM || h < 0 || h >= HDIM) continue;
        const int wbase = w0 - 4 + q * 4;
        const float* rowp = target + ((size_t)(b * DDIM + d) * HDIM + h) * WDIM;
        unsigned fgn = 0u, vn = 0u;
        if (wbase >= 0 && wbase <= WDIM - 4) {
            float4 v4 = *(const float4*)(rowp + wbase);
            fgn = (unsigned)(v4.x > 0.5f) | ((unsigned)(v4.y > 0.5f) << 1) |
                  ((unsigned)(v4.z > 0.5f) << 2) | ((unsigned)(v4.w > 0.5f) << 3);
            vn = 0xFu;
        } else {
            for (int j = 0; j < 4; ++j) {
                int w = wbase + j;
                if (w >= 0 && w < WDIM) {
                    vn |= 1u << j;
                    if (rowp[w] > 0.5f) fgn |= 1u << j;
                }
            }
        }
        if (vn) {
            const int k = q * 4, word = k >> 5, sh = k & 31;
            if (fgn) atomicOr(&fgb[row * 2 + word], fgn << sh);
            atomicOr(&vbb[row * 2 + word], vn << sh);
        }
    }
    __syncthreads();

    // ---- W pass: bits -> capped dist2 (uint8), all 384 rows x 32 interior w ----
    for (int idx = tid; idx < NROWS * WT; idx += 256) {
        const int row = idx >> 5, wi = idx & 31;
        unsigned long long fg = ((unsigned long long)fgb[row * 2 + 1] << 32) | fgb[row * 2];
        unsigned long long vv = ((unsigned long long)vbb[row * 2 + 1] << 32) | vbb[row * 2];
        unsigned of = (unsigned)(fg >> wi) & 0x1FFu;        // window bits w-4..w+4
        unsigned ov = (unsigned)(vv >> wi) & 0x1FFu;
        unsigned ob = ~of & ov;                              // background & in-volume
        swn[idx] = (unsigned char)nearest2i(of);             // dist2 to nearest fg
        swp[idx] = (unsigned char)nearest2i(ob);             // dist2 to nearest bg
    }
    __syncthreads();

    // ---- H pass: 9-tap integer min-plus, rows 24d x 8 interior h x 32 w ----
    for (int idx = tid; idx < DH * HT * WT; idx += 256) {
        const int dr = idx >> 8;            // / (HT*WT)
        const int hh = (idx >> 5) & 7;
        const int wi = idx & 31;
        unsigned p = 25u, n = 25u;
        #pragma unroll
        for (int t = 0; t < 9; ++t) {
            const unsigned d2 = (unsigned)((t - 4) * (t - 4));
            const int src = (dr * HH + hh + t) * WT + wi;    // h window rows hh..hh+8
            p = min(p, d2 + (unsigned)swp[src]);
            n = min(n, d2 + (unsigned)swn[src]);
        }
        whp[idx] = (unsigned char)p;
        whn[idx] = (unsigned char)n;
    }
    __syncthreads();

    // ---- D pass + loss: interior 16d x 8h x 32w = 4096 voxels ----
    float num = 0.f, den = 0.f;
    #pragma unroll 4
    for (int it = 0; it < 16; ++it) {
        const int idx = tid + 256 * it;
        const int di = idx >> 8;
        const int hh = (idx >> 5) & 7;
        const int wi = idx & 31;
        unsigned p = 25u, n = 25u;
        #pragma unroll
        for (int t = 0; t < 9; ++t) {
            const unsigned d2 = (unsigned)((t - 4) * (t - 4));
            const int src = ((di + t) * HT + hh) * WT + wi;  // d window slabs di..di+8
            p = min(p, d2 + (unsigned)whp[src]);
            n = min(n, d2 + (unsigned)whn[src]);
        }
        const size_t g = ((size_t)(b * DDIM + d0 + di) * HDIM + h0 + hh) * WDIM + w0 + wi;
        const float pr = pred[g];
        const float tg = target[g];
        const float dp = sqrtf((float)p);
        const float dn = sqrtf((float)n);
        const float a  = fabsf(dn - dp);
        float w;
        if (a <= 3.0f)      w = 1.0f;
        else if (a >= 5.0f) w = 0.0f;
        else                w = 1.0f - (a - 3.0f) * 0.5f;
        const float lp  = fmaxf(logf(pr), -100.0f);
        const float l1  = fmaxf(logf(1.0f - pr), -100.0f);
        const float bce = -(tg * lp + (1.0f - tg) * l1);
        num += bce * w;
        den += w;
    }

    // ---- wave reduce -> cross-wave LDS -> one atomic pair per block ----
    for (int off = 32; off > 0; off >>= 1) {
        num += __shfl_down(num, off);
        den += __shfl_down(den, off);
    }
    if ((tid & 63) == 0) {
        rsum[tid >> 6]       = num;
        rsum[4 + (tid >> 6)] = den;
    }
    __syncthreads();
    if (tid == 0) {
        float ns = rsum[0] + rsum[1] + rsum[2] + rsum[3];
        float ds = rsum[4] + rsum[5] + rsum[6] + rsum[7];
        atomicAdd(&acc[b], ns);
        atomicAdd(&acc[2 + b], ds);
        __threadfence();
        int done = atomicAdd((int*)acc + 4, 1);
        if (done == NBLK - 1) {             // last block: finalize
            __threadfence();
            float n0 = atomicAdd(&acc[0], 0.0f);
            float n1 = atomicAdd(&acc[1], 0.0f);
            float d0_ = atomicAdd(&acc[2], 0.0f);
            float d1_ = atomicAdd(&acc[3], 0.0f);
            out[0] = 0.5f * (n0 / (d0_ + 1e-5f) + n1 / (d1_ + 1e-5f));
        }
    }
}

extern "C" void kernel_launch(void* const* d_in, const int* in_sizes, int n_in,
                              void* d_out, int out_size, void* d_ws, size_t ws_size,
                              hipStream_t stream) {
    const float* pred   = (const float*)d_in[0];
    const float* target = (const float*)d_in[1];
    float* acc = (float*)d_ws;          // 4 floats num/den + 1 int counter
    float* out = (float*)d_out;

    init_acc<<<1, 64, 0, stream>>>(acc);
    boundary_fused<<<NBLK, 256, 0, stream>>>(pred, target, acc, out);
}